// Round 1
// baseline (696.554 us; speedup 1.0000x reference)
//
#include <hip/hip_runtime.h>
#include <hip/hip_bf16.h>

#define DIM 256
#define SEQ 256
#define NB 4096
#define OUT_STRIDE 3073

typedef float f32x4 __attribute__((ext_vector_type(4)));
typedef __bf16 bf16x8 __attribute__((ext_vector_type(8)));
typedef unsigned short u16;
typedef unsigned int u32;

__device__ __forceinline__ float bf2f(u16 h){ return __uint_as_float(((u32)h)<<16); }
__device__ __forceinline__ u16 f2bf(float f){
  u32 u = __float_as_uint(f);
  return (u16)((u + 0x7FFFu + ((u>>16)&1u)) >> 16);
}

__device__ const int d_nsrc[10] = {0,1,2,1,2,2,3,2,3,3};
__device__ const int d_srcs[10][3] = {{0,0,0},{0,0,0},{0,1,0},{1,0,0},{2,3,0},
                                      {2,4,0},{1,3,5},{4,5,0},{5,6,7},{6,7,8}};

// ---------------- table f32 -> bf16 ----------------
__global__ void k_convert_table(const float* __restrict__ src, u16* __restrict__ dst, int n4){
  int i = blockIdx.x*blockDim.x + threadIdx.x;
  if (i >= n4) return;
  float4 v = ((const float4*)src)[i];
  ushort4 o; o.x=f2bf(v.x); o.y=f2bf(v.y); o.z=f2bf(v.z); o.w=f2bf(v.w);
  ((ushort4*)dst)[i] = o;
}

// ---------------- weight pack into MFMA B-fragment layout ----------------
// dst group g (8 bf16): value j = W[kk*32 + (lane>>4)*8 + j][t*16 + (lane&15)]
// with g = segLayout(matrix, kk, t, lane)
__global__ void k_pack(const float* __restrict__ nw1, const float* __restrict__ nw2,
                       const float* __restrict__ rw,  const float* __restrict__ ww1,
                       const float* __restrict__ ww2, const float* __restrict__ tw1,
                       const float* __restrict__ tw2, const float* __restrict__ cw,
                       const float* __restrict__ sw1, u16* __restrict__ dst){
  int g = blockIdx.x*blockDim.x + threadIdx.x;
  if (g >= 344064) return;
  const float* base; int gpm, K, N, segStart;
  if      (g < 81920) { base=nw1; gpm=8192; K=256; N=256; segStart=0; }
  else if (g < 163840){ base=nw2; gpm=8192; K=256; N=256; segStart=81920; }
  else if (g < 245760){ base=rw;  gpm=8192; K=256; N=256; segStart=163840; }
  else if (g < 278528){ base=ww1; gpm=8192; K=256; N=256; segStart=245760; }
  else if (g < 311296){ base=ww2; gpm=8192; K=256; N=256; segStart=278528; }
  else if (g < 315392){ base=tw1; gpm=4096; K=256; N=128; segStart=311296; }
  else if (g < 319488){ base=tw2; gpm=4096; K=128; N=256; segStart=315392; }
  else if (g < 327680){ base=cw;  gpm=8192; K=256; N=256; segStart=319488; }
  else                { base=sw1; gpm=16384;K=256; N=512; segStart=327680; }
  int gs = g - segStart;
  int mat = gs / gpm, gl = gs % gpm;
  int lane = gl & 63, g2 = gl >> 6;
  int Nt = N >> 4;
  int t = g2 % Nt, kk = g2 / Nt;
  int col = t*16 + (lane & 15);
  int k0  = kk*32 + (lane >> 4)*8;
  const float* m = base + (size_t)mat*K*N;
  u16* o = dst + (size_t)g*8;
  (void)K;
  #pragma unroll
  for (int j=0;j<8;j++) o[j] = f2bf(m[(size_t)(k0+j)*N + col]);
}

// ---------------- embedding gather + mean ----------------
template<typename T>
__global__ void k_embed(const int* __restrict__ x, const T* __restrict__ table, u16* __restrict__ emb){
  __shared__ float red[4][256];
  int b = blockIdx.x;
  int tid = threadIdx.x, w = tid>>6, lane = tid&63;
  const int* xb = x + b*SEQ;
  float a0=0.f,a1=0.f,a2=0.f,a3=0.f;
  #pragma unroll 4
  for (int ii=0; ii<64; ii++){
    int idx = xb[w*64+ii];
    if constexpr (sizeof(T)==2){
      ushort4 v = *(const ushort4*)(table + (size_t)idx*DIM + lane*4);
      a0+=bf2f(v.x); a1+=bf2f(v.y); a2+=bf2f(v.z); a3+=bf2f(v.w);
    } else {
      float4 v = *(const float4*)(table + (size_t)idx*DIM + lane*4);
      a0+=v.x; a1+=v.y; a2+=v.z; a3+=v.w;
    }
  }
  red[w][lane*4+0]=a0; red[w][lane*4+1]=a1; red[w][lane*4+2]=a2; red[w][lane*4+3]=a3;
  __syncthreads();
  float s = (red[0][tid]+red[1][tid]+red[2][tid]+red[3][tid]) * (1.0f/SEQ);
  emb[(size_t)b*DIM + tid] = f2bf(s);
}

// ---------------- main fused network ----------------
__device__ __forceinline__ bf16x8 lds_readA(const u16* base, int rs, int kk, int lane){
  int row = lane & 15;
  int kbyte = kk*64 + (lane>>4)*16;
  return *(const bf16x8*)((const char*)base + row*rs + (kbyte ^ ((row&7)<<4)));
}

template<int NPW, int NT, int KS>
__device__ __forceinline__ void gemm_pass(const u16* A, int rs, const bf16x8* __restrict__ wfb,
                                          f32x4* acc, int wave, int lane){
  #pragma unroll
  for (int kk=0; kk<KS; kk++){
    bf16x8 a = lds_readA(A, rs, kk, lane);
    #pragma unroll
    for (int t=0; t<NPW; t++){
      bf16x8 b = wfb[((size_t)(kk*NT + wave*NPW + t))*64 + lane];
      acc[t] = __builtin_amdgcn_mfma_f32_16x16x32_bf16(a, b, acc[t], 0, 0, 0);
    }
  }
}

template<int NPW>
__device__ __forceinline__ void acc_init(f32x4* acc, const float* __restrict__ b1,
                                         const float* __restrict__ b2, int wave, int lane){
  #pragma unroll
  for (int t=0;t<NPW;t++){
    int col = (wave*NPW+t)*16 + (lane&15);
    float bv = b1 ? b1[col] : 0.0f;
    if (b2) bv += b2[col];
    f32x4 tmp = {bv,bv,bv,bv};
    acc[t] = tmp;
  }
}

template<int NPW, bool GELU>
__device__ __forceinline__ void epi_store(const f32x4* acc, u16* dst, int rs, int wave, int lane,
                                          const float* __restrict__ addcol){
  #pragma unroll
  for (int t=0;t<NPW;t++){
    int col = (wave*NPW+t)*16 + (lane&15);
    float add = addcol ? addcol[col] : 0.0f;
    #pragma unroll
    for (int r=0;r<4;r++){
      int row = (lane>>4)*4 + r;
      float v = acc[t][r];
      if (GELU) v = 0.5f*v*(1.0f + erff(v*0.70710678118654752f));
      v += add;
      *(u16*)((char*)dst + row*rs + ((col*2) ^ ((row&7)<<4))) = f2bf(v);
    }
  }
}

__device__ __forceinline__ void out_write(const u16* buf, int rs, float* __restrict__ out,
                                          size_t rowBase, int colBase, int wave, int lane){
  #pragma unroll
  for (int rr=0; rr<4; rr++){
    int r = wave*4 + rr;
    int sw = (r&7)<<4;
    #pragma unroll
    for (int cc=0; cc<4; cc++){
      int c = cc*64 + lane;
      float v = bf2f(*(const u16*)((const char*)buf + r*rs + ((c*2)^sw)));
      out[(rowBase + r)*OUT_STRIDE + colBase + c] = v;
    }
  }
}

__global__ __launch_bounds__(256,1) void k_main(
  const u16* __restrict__ wfrag, const u16* __restrict__ emb,
  const float* __restrict__ nb1, const float* __restrict__ nb2, const float* __restrict__ rb,
  const float* __restrict__ wb1, const float* __restrict__ wb2,
  const float* __restrict__ tb1, const float* __restrict__ tb2,
  const float* __restrict__ voidv, const float* __restrict__ cb,
  const float* __restrict__ sb1, const float* __restrict__ sb2, const float* __restrict__ sw2,
  const int* __restrict__ niter_p, float* __restrict__ out)
{
  __shared__ u16 states[10][16][256];   // XOR-swizzled, rs=512B
  __shared__ u16 abuf[16][512];         // rs=1024B: [:,0:256]=h1/hidden/created, [:,256:512]=inc
  __shared__ u16 cbuf[16][256];         // rs=512B : cur / contracted+void
  __shared__ u16 hbuf[16][512];         // rs=1024B: shek hidden
  __shared__ float red[16][17];

  const int tid = threadIdx.x, wave = tid>>6, lane = tid&63;
  const int blk = blockIdx.x;
  const int niter = *niter_p;
  const bf16x8* wf = (const bf16x8*)wfrag;

  // load embedded -> all 10 states (swizzled)
  {
    int r = tid >> 4, c0 = (tid & 15) * 16;
    const bf16x8* g = (const bf16x8*)(emb + ((size_t)(blk*16 + r))*DIM + c0);
    bf16x8 v0 = g[0], v1 = g[1];
    int sw = (r&7)<<4;
    #pragma unroll
    for (int st=0; st<10; st++){
      char* bp = (char*)states[st];
      *(bf16x8*)(bp + r*512 + ((c0*2)    ^ sw)) = v0;
      *(bf16x8*)(bp + r*512 + ((c0*2+16) ^ sw)) = v1;
    }
  }
  __syncthreads();

  for (int it=0; it<niter; it++){
    for (int i=0; i<10; i++){
      int ns = d_nsrc[i];
      // stage A: h1 = gelu(states[i] @ W1_i + b1_i) -> abuf[:,0:256]
      f32x4 accA[4];
      acc_init<4>(accA, nb1 + i*DIM, nullptr, wave, lane);
      gemm_pass<4,16,8>(&states[i][0][0], 512, wf + (size_t)i*8192, accA, wave, lane);
      epi_store<4,true>(accA, &abuf[0][0], 1024, wave, lane, nullptr);
      // inc = sum(states[srcs]) -> abuf[:,256:512]
      if (ns > 0){
        int r = tid>>4, c0 = (tid&15)*16, sw = (r&7)<<4;
        const char* s0 = (const char*)states[d_srcs[i][0]];
        const char* s1 = (ns>1) ? (const char*)states[d_srcs[i][1]] : nullptr;
        const char* s2 = (ns>2) ? (const char*)states[d_srcs[i][2]] : nullptr;
        #pragma unroll
        for (int q=0;q<16;q++){
          int cbyte = ((c0+q)*2) ^ sw;
          float v = bf2f(*(const u16*)(s0 + r*512 + cbyte));
          if (s1) v += bf2f(*(const u16*)(s1 + r*512 + cbyte));
          if (s2) v += bf2f(*(const u16*)(s2 + r*512 + cbyte));
          *(u16*)((char*)abuf + r*1024 + 512 + cbyte) = f2bf(v);
        }
      }
      __syncthreads();
      // stage B: states[i] = h1 @ W2_i + b2 [+ inc @ recvW_i + recv_b]
      f32x4 accB[4];
      acc_init<4>(accB, nb2 + i*DIM, (ns>0) ? (rb + i*DIM) : nullptr, wave, lane);
      gemm_pass<4,16,8>(&abuf[0][0], 1024, wf + 81920 + (size_t)i*8192, accB, wave, lane);
      if (ns > 0)
        gemm_pass<4,16,8>((const u16*)((const char*)&abuf[0][0] + 512), 1024,
                          wf + 163840 + (size_t)i*8192, accB, wave, lane);
      epi_store<4,false>(accB, &states[i][0][0], 512, wave, lane, nullptr);
      __syncthreads();
    }
  }

  // worlds
  for (int w=0; w<4; w++){
    f32x4 acc1[4];
    acc_init<4>(acc1, wb1 + w*DIM, nullptr, wave, lane);
    const u16* A = (w==0) ? &states[9][0][0] : &cbuf[0][0];
    gemm_pass<4,16,8>(A, 512, wf + 245760 + (size_t)w*8192, acc1, wave, lane);
    epi_store<4,true>(acc1, &abuf[0][0], 1024, wave, lane, nullptr);
    __syncthreads();
    f32x4 acc2[4];
    acc_init<4>(acc2, wb2 + w*DIM, nullptr, wave, lane);
    gemm_pass<4,16,8>(&abuf[0][0], 1024, wf + 278528 + (size_t)w*8192, acc2, wave, lane);
    epi_store<4,false>(acc2, &cbuf[0][0], 512, wave, lane, nullptr);
    __syncthreads();
  }
  // cur -> out[:,2560:2816]
  out_write(&cbuf[0][0], 512, out, (size_t)blk*16, 2560, wave, lane);

  // tz1: hidden = gelu(cur @ tz_w1 + tb1), N=128 -> abuf[:,0:128]
  {
    f32x4 acc[2];
    acc_init<2>(acc, tb1, nullptr, wave, lane);
    gemm_pass<2,8,8>(&cbuf[0][0], 512, wf + 311296, acc, wave, lane);
    epi_store<2,true>(acc, &abuf[0][0], 1024, wave, lane, nullptr);
    __syncthreads();
  }
  // tz2: ctv = (hidden @ tz_w2 + tb2) + void  -> cbuf
  {
    f32x4 acc[4];
    acc_init<4>(acc, tb2, nullptr, wave, lane);
    gemm_pass<4,16,4>(&abuf[0][0], 1024, wf + 315392, acc, wave, lane);
    epi_store<4,false>(acc, &cbuf[0][0], 512, wave, lane, voidv);
    __syncthreads();
  }
  // cre: created = ctv @ cre_w + cre_b -> abuf[:,0:256]
  {
    f32x4 acc[4];
    acc_init<4>(acc, cb, nullptr, wave, lane);
    gemm_pass<4,16,8>(&cbuf[0][0], 512, wf + 319488, acc, wave, lane);
    epi_store<4,false>(acc, &abuf[0][0], 1024, wave, lane, nullptr);
    __syncthreads();
  }
  // shek1: h = gelu(created @ shek_w1 + sb1), N=512 -> hbuf
  {
    f32x4 acc[8];
    acc_init<8>(acc, sb1, nullptr, wave, lane);
    gemm_pass<8,32,8>(&abuf[0][0], 1024, wf + 327680, acc, wave, lane);
    epi_store<8,true>(acc, &hbuf[0][0], 1024, wave, lane, nullptr);
    __syncthreads();
  }
  // shek2: sigmoid(h @ sw2 + sb2) -> out[:,3072]
  {
    int r = tid>>4, p = tid&15;
    int sw = (r&7)<<4;
    float partial = 0.f;
    #pragma unroll
    for (int j=0;j<32;j++){
      int k = p*32+j;
      partial += bf2f(*(const u16*)((const char*)hbuf + r*1024 + ((k*2)^sw))) * sw2[k];
    }
    red[r][p] = partial;
    __syncthreads();
    if (tid < 16){
      float s = sb2[0];
      #pragma unroll
      for (int p2=0;p2<16;p2++) s += red[tid][p2];
      out[((size_t)(blk*16+tid))*OUT_STRIDE + 3072] = 1.f/(1.f+expf(-s));
    }
  }

  // states -> out[:,0:2560], created -> out[:,2816:3072]
  #pragma unroll
  for (int st=0; st<10; st++)
    out_write(&states[st][0][0], 512, out, (size_t)blk*16, st*256, wave, lane);
  out_write(&abuf[0][0], 1024, out, (size_t)blk*16, 2816, wave, lane);
}

extern "C" void kernel_launch(void* const* d_in, const int* in_sizes, int n_in,
                              void* d_out, int out_size, void* d_ws, size_t ws_size,
                              hipStream_t stream){
  const int*   x     = (const int*)d_in[0];
  const int*   nitp  = (const int*)d_in[1];
  const float* table = (const float*)d_in[2];
  const float* nw1   = (const float*)d_in[3];
  const float* nb1   = (const float*)d_in[4];
  const float* nw2   = (const float*)d_in[5];
  const float* nb2   = (const float*)d_in[6];
  const float* rw    = (const float*)d_in[7];
  const float* rb    = (const float*)d_in[8];
  const float* ww1   = (const float*)d_in[9];
  const float* wb1   = (const float*)d_in[10];
  const float* ww2   = (const float*)d_in[11];
  const float* wb2   = (const float*)d_in[12];
  const float* tw1   = (const float*)d_in[13];
  const float* tb1   = (const float*)d_in[14];
  const float* tw2   = (const float*)d_in[15];
  const float* tb2   = (const float*)d_in[16];
  const float* voidv = (const float*)d_in[17];
  const float* cw    = (const float*)d_in[18];
  const float* cb    = (const float*)d_in[19];
  const float* sw1   = (const float*)d_in[20];
  const float* sb1   = (const float*)d_in[21];
  const float* sw2   = (const float*)d_in[22];
  const float* sb2   = (const float*)d_in[23];
  float* out = (float*)d_out;
  char* ws = (char*)d_ws;

  const size_t TBL_BYTES = (size_t)50257*256*2;   // 25,731,584
  const size_t WF_BYTES  = (size_t)344064*8*2;    //  5,505,024
  const size_t EMB_BYTES = (size_t)4096*256*2;    //  2,097,152
  bool big = ws_size >= TBL_BYTES + WF_BYTES + EMB_BYTES;

  u16 *tbl16, *wfrag, *emb;
  if (big){ tbl16=(u16*)ws; wfrag=(u16*)(ws+TBL_BYTES); emb=(u16*)(ws+TBL_BYTES+WF_BYTES); }
  else    { tbl16=nullptr;  wfrag=(u16*)ws;             emb=(u16*)(ws+WF_BYTES); }

  k_pack<<<1344, 256, 0, stream>>>(nw1,nw2,rw,ww1,ww2,tw1,tw2,cw,sw1,wfrag);
  if (big){
    k_convert_table<<<(3216448+255)/256, 256, 0, stream>>>(table, tbl16, 3216448);
    k_embed<u16><<<NB, 256, 0, stream>>>(x, tbl16, emb);
  } else {
    k_embed<float><<<NB, 256, 0, stream>>>(x, table, emb);
  }
  k_main<<<256, 256, 0, stream>>>(wfrag, emb, nb1, nb2, rb, wb1, wb2, tb1, tb2,
                                  voidv, cb, sb1, sb2, sw2, nitp, out);
}

// Round 2
// 292.189 us; speedup vs baseline: 2.3839x; 2.3839x over previous
//
#include <hip/hip_runtime.h>
#include <hip/hip_bf16.h>

#define DIM 256
#define SEQ 256
#define NB 4096
#define OUT_STRIDE 3073

typedef float f32x4 __attribute__((ext_vector_type(4)));
typedef __bf16 bf16x8 __attribute__((ext_vector_type(8)));
typedef unsigned short u16;
typedef unsigned int u32;

__device__ __forceinline__ float bf2f(u16 h){ return __uint_as_float(((u32)h)<<16); }
__device__ __forceinline__ u16 f2bf(float f){
  u32 u = __float_as_uint(f);
  return (u16)((u + 0x7FFFu + ((u>>16)&1u)) >> 16);
}

__device__ const int d_nsrc[10] = {0,1,2,1,2,2,3,2,3,3};
__device__ const int d_srcs[10][3] = {{0,0,0},{0,0,0},{0,1,0},{1,0,0},{2,3,0},
                                      {2,4,0},{1,3,5},{4,5,0},{5,6,7},{6,7,8}};

// ---------------- table f32 -> bf16 ----------------
__global__ void k_convert_table(const float* __restrict__ src, u16* __restrict__ dst, int n4){
  int i = blockIdx.x*blockDim.x + threadIdx.x;
  if (i >= n4) return;
  float4 v = ((const float4*)src)[i];
  ushort4 o; o.x=f2bf(v.x); o.y=f2bf(v.y); o.z=f2bf(v.z); o.w=f2bf(v.w);
  ((ushort4*)dst)[i] = o;
}

// ---------------- weight pack into MFMA B-fragment layout ----------------
__global__ void k_pack(const float* __restrict__ nw1, const float* __restrict__ nw2,
                       const float* __restrict__ rw,  const float* __restrict__ ww1,
                       const float* __restrict__ ww2, const float* __restrict__ tw1,
                       const float* __restrict__ tw2, const float* __restrict__ cw,
                       const float* __restrict__ sw1, u16* __restrict__ dst){
  int g = blockIdx.x*blockDim.x + threadIdx.x;
  if (g >= 344064) return;
  const float* base; int gpm, K, N, segStart;
  if      (g < 81920) { base=nw1; gpm=8192; K=256; N=256; segStart=0; }
  else if (g < 163840){ base=nw2; gpm=8192; K=256; N=256; segStart=81920; }
  else if (g < 245760){ base=rw;  gpm=8192; K=256; N=256; segStart=163840; }
  else if (g < 278528){ base=ww1; gpm=8192; K=256; N=256; segStart=245760; }
  else if (g < 311296){ base=ww2; gpm=8192; K=256; N=256; segStart=278528; }
  else if (g < 315392){ base=tw1; gpm=4096; K=256; N=128; segStart=311296; }
  else if (g < 319488){ base=tw2; gpm=4096; K=128; N=256; segStart=315392; }
  else if (g < 327680){ base=cw;  gpm=8192; K=256; N=256; segStart=319488; }
  else                { base=sw1; gpm=16384;K=256; N=512; segStart=327680; }
  int gs = g - segStart;
  int mat = gs / gpm, gl = gs % gpm;
  int lane = gl & 63, g2 = gl >> 6;
  int Nt = N >> 4;
  int t = g2 % Nt, kk = g2 / Nt;
  int col = t*16 + (lane & 15);
  int k0  = kk*32 + (lane >> 4)*8;
  const float* m = base + (size_t)mat*K*N;
  u16* o = dst + (size_t)g*8;
  (void)K;
  #pragma unroll
  for (int j=0;j<8;j++) o[j] = f2bf(m[(size_t)(k0+j)*N + col]);
}

// ---------------- embedding gather + mean ----------------
template<typename T>
__global__ void k_embed(const int* __restrict__ x, const T* __restrict__ table, u16* __restrict__ emb){
  __shared__ float red[4][256];
  int b = blockIdx.x;
  int tid = threadIdx.x, w = tid>>6, lane = tid&63;
  const int* xb = x + b*SEQ;
  float a0=0.f,a1=0.f,a2=0.f,a3=0.f;
  #pragma unroll 4
  for (int ii=0; ii<64; ii++){
    int idx = xb[w*64+ii];
    if constexpr (sizeof(T)==2){
      ushort4 v = *(const ushort4*)(table + (size_t)idx*DIM + lane*4);
      a0+=bf2f(v.x); a1+=bf2f(v.y); a2+=bf2f(v.z); a3+=bf2f(v.w);
    } else {
      float4 v = *(const float4*)(table + (size_t)idx*DIM + lane*4);
      a0+=v.x; a1+=v.y; a2+=v.z; a3+=v.w;
    }
  }
  red[w][lane*4+0]=a0; red[w][lane*4+1]=a1; red[w][lane*4+2]=a2; red[w][lane*4+3]=a3;
  __syncthreads();
  float s = (red[0][tid]+red[1][tid]+red[2][tid]+red[3][tid]) * (1.0f/SEQ);
  emb[(size_t)b*DIM + tid] = f2bf(s);
}

// ---------------- main fused network ----------------
__device__ __forceinline__ bf16x8 lds_readA(const u16* base, int rs, int kk, int lane){
  int row = lane & 15;
  int kbyte = kk*64 + (lane>>4)*16;
  return *(const bf16x8*)((const char*)base + row*rs + (kbyte ^ ((row&7)<<4)));
}

// Prefetch ALL B fragments of the pass into registers, THEN run the MFMAs.
// One L2/L3 latency exposure per pass instead of KS*NPW serial exposures.
template<int NPW, int NT, int KS>
__device__ __forceinline__ void gemm_pass(const u16* A, int rs, const bf16x8* __restrict__ wfb,
                                          f32x4* acc, int wave, int lane, int kk0 = 0){
  bf16x8 b[KS][NPW];
  #pragma unroll
  for (int kk=0; kk<KS; kk++)
    #pragma unroll
    for (int t=0; t<NPW; t++)
      b[kk][t] = wfb[((size_t)((kk0+kk)*NT + wave*NPW + t))*64 + lane];
  #pragma unroll
  for (int kk=0; kk<KS; kk++){
    bf16x8 a = lds_readA(A, rs, kk0+kk, lane);
    #pragma unroll
    for (int t=0; t<NPW; t++)
      acc[t] = __builtin_amdgcn_mfma_f32_16x16x32_bf16(a, b[kk][t], acc[t], 0, 0, 0);
  }
}

template<int NPW>
__device__ __forceinline__ void acc_init(f32x4* acc, const float* __restrict__ b1,
                                         const float* __restrict__ b2, int wave, int lane){
  #pragma unroll
  for (int t=0;t<NPW;t++){
    int col = (wave*NPW+t)*16 + (lane&15);
    float bv = b1 ? b1[col] : 0.0f;
    if (b2) bv += b2[col];
    f32x4 tmp = {bv,bv,bv,bv};
    acc[t] = tmp;
  }
}

template<int NPW, bool GELU>
__device__ __forceinline__ void epi_store(const f32x4* acc, u16* dst, int rs, int wave, int lane,
                                          const float* __restrict__ addcol){
  #pragma unroll
  for (int t=0;t<NPW;t++){
    int col = (wave*NPW+t)*16 + (lane&15);
    float add = addcol ? addcol[col] : 0.0f;
    #pragma unroll
    for (int r=0;r<4;r++){
      int row = (lane>>4)*4 + r;
      float v = acc[t][r];
      if (GELU) v = 0.5f*v*(1.0f + erff(v*0.70710678118654752f));
      v += add;
      *(u16*)((char*)dst + row*rs + ((col*2) ^ ((row&7)<<4))) = f2bf(v);
    }
  }
}

// 16 waves: wave w writes row w (16 rows), 4 chunks of 64 cols
__device__ __forceinline__ void out_write(const u16* buf, int rs, float* __restrict__ out,
                                          size_t rowBase, int colBase, int wave, int lane){
  int r = wave;
  int sw = (r&7)<<4;
  #pragma unroll
  for (int cc=0; cc<4; cc++){
    int c = cc*64 + lane;
    float v = bf2f(*(const u16*)((const char*)buf + r*rs + ((c*2)^sw)));
    out[(rowBase + r)*OUT_STRIDE + colBase + c] = v;
  }
}

__global__ __launch_bounds__(1024,4) void k_main(
  const u16* __restrict__ wfrag, const u16* __restrict__ emb,
  const float* __restrict__ nb1, const float* __restrict__ nb2, const float* __restrict__ rb,
  const float* __restrict__ wb1, const float* __restrict__ wb2,
  const float* __restrict__ tb1, const float* __restrict__ tb2,
  const float* __restrict__ voidv, const float* __restrict__ cb,
  const float* __restrict__ sb1, const float* __restrict__ sb2, const float* __restrict__ sw2,
  const int* __restrict__ niter_p, float* __restrict__ out)
{
  __shared__ u16 states[10][16][256];   // XOR-swizzled, rs=512B
  __shared__ u16 abuf[16][512];         // rs=1024B: [:,0:256]=h1/hidden/created, [:,256:512]=inc
  __shared__ u16 cbuf[16][256];         // rs=512B : cur / contracted+void
  __shared__ u16 hbuf[16][512];         // rs=1024B: shek hidden
  __shared__ float red[16][65];

  const int tid = threadIdx.x, wave = tid>>6, lane = tid&63;
  const int blk = blockIdx.x;
  const int niter = *niter_p;
  const bf16x8* wf = (const bf16x8*)wfrag;

  // load embedded -> all 10 states (swizzled). 1024 threads: 4 bf16 (8B) each.
  {
    int r = tid >> 6, c0 = (tid & 63) * 4;
    uint2 v = *(const uint2*)(emb + ((size_t)(blk*16 + r))*DIM + c0);
    int sw = (r&7)<<4;
    #pragma unroll
    for (int st=0; st<10; st++){
      char* bp = (char*)states[st];
      *(uint2*)(bp + r*512 + ((c0*2) ^ sw)) = v;
    }
  }
  __syncthreads();

  for (int it=0; it<niter; it++){
    for (int i=0; i<10; i++){
      int ns = d_nsrc[i];
      // stage A: h1 = gelu(states[i] @ W1_i + b1_i) -> abuf[:,0:256]
      f32x4 accA[1];
      acc_init<1>(accA, nb1 + i*DIM, nullptr, wave, lane);
      gemm_pass<1,16,8>(&states[i][0][0], 512, wf + (size_t)i*8192, accA, wave, lane);
      epi_store<1,true>(accA, &abuf[0][0], 1024, wave, lane, nullptr);
      // inc = sum(states[srcs]) -> abuf[:,256:512]
      if (ns > 0){
        int r = tid>>6, c0 = (tid&63)*4, sw = (r&7)<<4;
        const char* s0 = (const char*)states[d_srcs[i][0]];
        const char* s1 = (ns>1) ? (const char*)states[d_srcs[i][1]] : nullptr;
        const char* s2 = (ns>2) ? (const char*)states[d_srcs[i][2]] : nullptr;
        #pragma unroll
        for (int q=0;q<4;q++){
          int cbyte = ((c0+q)*2) ^ sw;
          float v = bf2f(*(const u16*)(s0 + r*512 + cbyte));
          if (s1) v += bf2f(*(const u16*)(s1 + r*512 + cbyte));
          if (s2) v += bf2f(*(const u16*)(s2 + r*512 + cbyte));
          *(u16*)((char*)abuf + r*1024 + 512 + cbyte) = f2bf(v);
        }
      }
      __syncthreads();
      // stage B: states[i] = h1 @ W2_i + b2 [+ inc @ recvW_i + recv_b]
      f32x4 accB[1];
      acc_init<1>(accB, nb2 + i*DIM, (ns>0) ? (rb + i*DIM) : nullptr, wave, lane);
      gemm_pass<1,16,8>(&abuf[0][0], 1024, wf + 81920 + (size_t)i*8192, accB, wave, lane);
      if (ns > 0)
        gemm_pass<1,16,8>((const u16*)((const char*)&abuf[0][0] + 512), 1024,
                          wf + 163840 + (size_t)i*8192, accB, wave, lane);
      epi_store<1,false>(accB, &states[i][0][0], 512, wave, lane, nullptr);
      __syncthreads();
    }
  }

  // worlds
  for (int w=0; w<4; w++){
    f32x4 acc1[1];
    acc_init<1>(acc1, wb1 + w*DIM, nullptr, wave, lane);
    const u16* A = (w==0) ? &states[9][0][0] : &cbuf[0][0];
    gemm_pass<1,16,8>(A, 512, wf + 245760 + (size_t)w*8192, acc1, wave, lane);
    epi_store<1,true>(acc1, &abuf[0][0], 1024, wave, lane, nullptr);
    __syncthreads();
    f32x4 acc2[1];
    acc_init<1>(acc2, wb2 + w*DIM, nullptr, wave, lane);
    gemm_pass<1,16,8>(&abuf[0][0], 1024, wf + 278528 + (size_t)w*8192, acc2, wave, lane);
    epi_store<1,false>(acc2, &cbuf[0][0], 512, wave, lane, nullptr);
    __syncthreads();
  }
  // cur -> out[:,2560:2816]
  out_write(&cbuf[0][0], 512, out, (size_t)blk*16, 2560, wave, lane);

  // tz1: hidden = gelu(cur @ tz_w1 + tb1), N=128 -> abuf[:,0:128] (waves 0-7 only)
  if (wave < 8){
    f32x4 acc[1];
    acc_init<1>(acc, tb1, nullptr, wave, lane);
    gemm_pass<1,8,8>(&cbuf[0][0], 512, wf + 311296, acc, wave, lane);
    epi_store<1,true>(acc, &abuf[0][0], 1024, wave, lane, nullptr);
  }
  __syncthreads();
  // tz2: ctv = (hidden @ tz_w2 + tb2) + void  -> cbuf
  {
    f32x4 acc[1];
    acc_init<1>(acc, tb2, nullptr, wave, lane);
    gemm_pass<1,16,4>(&abuf[0][0], 1024, wf + 315392, acc, wave, lane);
    epi_store<1,false>(acc, &cbuf[0][0], 512, wave, lane, voidv);
    __syncthreads();
  }
  // cre: created = ctv @ cre_w + cre_b -> abuf[:,0:256]
  {
    f32x4 acc[1];
    acc_init<1>(acc, cb, nullptr, wave, lane);
    gemm_pass<1,16,8>(&cbuf[0][0], 512, wf + 319488, acc, wave, lane);
    epi_store<1,false>(acc, &abuf[0][0], 1024, wave, lane, nullptr);
    __syncthreads();
  }
  // shek1: h = gelu(created @ shek_w1 + sb1), N=512 -> hbuf
  {
    f32x4 acc[2];
    acc_init<2>(acc, sb1, nullptr, wave, lane);
    gemm_pass<2,32,8>(&abuf[0][0], 1024, wf + 327680, acc, wave, lane);
    epi_store<2,true>(acc, &hbuf[0][0], 1024, wave, lane, nullptr);
    __syncthreads();
  }
  // shek2: sigmoid(h @ sw2 + sb2) -> out[:,3072]
  {
    int r = tid>>6, p = tid&63;
    int sw = (r&7)<<4;
    float partial = 0.f;
    #pragma unroll
    for (int j=0;j<8;j++){
      int k = p*8+j;
      partial += bf2f(*(const u16*)((const char*)hbuf + r*1024 + ((k*2)^sw))) * sw2[k];
    }
    red[r][p] = partial;
    __syncthreads();
    if (tid < 16){
      float s = sb2[0];
      #pragma unroll
      for (int p2=0;p2<64;p2++) s += red[tid][p2];
      out[((size_t)(blk*16+tid))*OUT_STRIDE + 3072] = 1.f/(1.f+expf(-s));
    }
  }

  // states -> out[:,0:2560], created -> out[:,2816:3072]
  #pragma unroll
  for (int st=0; st<10; st++)
    out_write(&states[st][0][0], 512, out, (size_t)blk*16, st*256, wave, lane);
  out_write(&abuf[0][0], 1024, out, (size_t)blk*16, 2816, wave, lane);
}

extern "C" void kernel_launch(void* const* d_in, const int* in_sizes, int n_in,
                              void* d_out, int out_size, void* d_ws, size_t ws_size,
                              hipStream_t stream){
  const int*   x     = (const int*)d_in[0];
  const int*   nitp  = (const int*)d_in[1];
  const float* table = (const float*)d_in[2];
  const float* nw1   = (const float*)d_in[3];
  const float* nb1   = (const float*)d_in[4];
  const float* nw2   = (const float*)d_in[5];
  const float* nb2   = (const float*)d_in[6];
  const float* rw    = (const float*)d_in[7];
  const float* rb    = (const float*)d_in[8];
  const float* ww1   = (const float*)d_in[9];
  const float* wb1   = (const float*)d_in[10];
  const float* ww2   = (const float*)d_in[11];
  const float* wb2   = (const float*)d_in[12];
  const float* tw1   = (const float*)d_in[13];
  const float* tb1   = (const float*)d_in[14];
  const float* tw2   = (const float*)d_in[15];
  const float* tb2   = (const float*)d_in[16];
  const float* voidv = (const float*)d_in[17];
  const float* cw    = (const float*)d_in[18];
  const float* cb    = (const float*)d_in[19];
  const float* sw1   = (const float*)d_in[20];
  const float* sb1   = (const float*)d_in[21];
  const float* sw2   = (const float*)d_in[22];
  const float* sb2   = (const float*)d_in[23];
  float* out = (float*)d_out;
  char* ws = (char*)d_ws;

  const size_t TBL_BYTES = (size_t)50257*256*2;   // 25,731,584
  const size_t WF_BYTES  = (size_t)344064*8*2;    //  5,505,024
  const size_t EMB_BYTES = (size_t)4096*256*2;    //  2,097,152
  bool big = ws_size >= TBL_BYTES + WF_BYTES + EMB_BYTES;

  u16 *tbl16, *wfrag, *emb;
  if (big){ tbl16=(u16*)ws; wfrag=(u16*)(ws+TBL_BYTES); emb=(u16*)(ws+TBL_BYTES+WF_BYTES); }
  else    { tbl16=nullptr;  wfrag=(u16*)ws;             emb=(u16*)(ws+WF_BYTES); }

  k_pack<<<1344, 256, 0, stream>>>(nw1,nw2,rw,ww1,ww2,tw1,tw2,cw,sw1,wfrag);
  if (big){
    k_convert_table<<<(3216448+255)/256, 256, 0, stream>>>(table, tbl16, 3216448);
    k_embed<u16><<<NB, 256, 0, stream>>>(x, tbl16, emb);
  } else {
    k_embed<float><<<NB, 256, 0, stream>>>(x, table, emb);
  }
  k_main<<<256, 1024, 0, stream>>>(wfrag, emb, nb1, nb2, rb, wb1, wb2, tb1, tb2,
                                   voidv, cb, sb1, sb2, sw2, nitp, out);
}